// Round 4
// baseline (398.287 us; speedup 1.0000x reference)
//
#include <hip/hip_runtime.h>
#include <hip/hip_bf16.h>

#define NPTS 131072
#define MCB  512
#define DIM  128
#define NRB  (NPTS/128)   // 1024 row blocks
#define NCBK (MCB/128)    // 4 col blocks
#define NBLK (NRB*NCBK)   // 4096 blocks

typedef __attribute__((ext_vector_type(4))) float  f32x4;
typedef __attribute__((ext_vector_type(8))) __bf16 bf16x8;
typedef unsigned short u16;
typedef unsigned int   u32;

// XOR-swizzle: permute 16B chunks within each 256B row by row&7. Involution.
__device__ __forceinline__ u32 swz(u32 p) { return p ^ (((p >> 8) & 7u) << 4); }

// f32 rows (len 128) -> bf16 + per-row sum of squares of the ROUNDED values.
__global__ __launch_bounds__(256) void convert_rows(const float* __restrict__ in,
                                                    u16* __restrict__ outb,
                                                    float* __restrict__ sq,
                                                    int nrows) {
  int wv = threadIdx.x >> 6, ln = threadIdx.x & 63;
  int half = ln >> 5, li = ln & 31;
  int npairs = nrows >> 1;
  for (int pr = blockIdx.x * 4 + wv; pr < npairs; pr += gridDim.x * 4) {
    int row = pr * 2 + half;
    const float4 v = *(const float4*)(in + (size_t)row * DIM + li * 4);
    __hip_bfloat16 b0 = __float2bfloat16(v.x);
    __hip_bfloat16 b1 = __float2bfloat16(v.y);
    __hip_bfloat16 b2 = __float2bfloat16(v.z);
    __hip_bfloat16 b3 = __float2bfloat16(v.w);
    ushort4 o;
    o.x = *(const u16*)&b0; o.y = *(const u16*)&b1;
    o.z = *(const u16*)&b2; o.w = *(const u16*)&b3;
    *(ushort4*)(outb + (size_t)row * DIM + li * 4) = o;
    float f0 = __bfloat162float(b0), f1 = __bfloat162float(b1);
    float f2 = __bfloat162float(b2), f3 = __bfloat162float(b3);
    float s = f0 * f0 + f1 * f1 + f2 * f2 + f3 * f3;
    s += __shfl_xor(s, 1); s += __shfl_xor(s, 2); s += __shfl_xor(s, 4);
    s += __shfl_xor(s, 8); s += __shfl_xor(s, 16);
    if (li == 0) sq[row] = s;
  }
}

// 128x128 tile, K=128 single LDS tile. B (codebook) staged in LDS (swizzled);
// A fragments loaded direct global->VGPR (A rows are wave-private, no reuse).
// WRITE=0: mfma(af,bfr) -> col sums of exp(-dist), in-lane over rows.
// WRITE=1: mfma(bfr,af) -> D-row = m, 4 consecutive m/thread -> dwordx4 stores.
template <int WRITE>
__global__ __launch_bounds__(256, 3) void gemm_pass(const u16* __restrict__ Xb,
                                                    const u16* __restrict__ Sb,
                                                    const float* __restrict__ x2,
                                                    const float* __restrict__ s2,
                                                    const float* __restrict__ invs,
                                                    float* __restrict__ outp) {
  __shared__ u16 Bt[128 * DIM];   // 32 KB, swizzled storage
  __shared__ float lx2[128], ls2[128], lscale[128];
  __shared__ float colsum2[4][64];

  int t = threadIdx.x, wv = t >> 6, ln = t & 63;
  u32 h = blockIdx.x;
  u32 l = (h & 7u) * (NBLK / 8) + (h >> 3);   // bijective XCD chunking
  u32 rb = l >> 2, cb = l & 3u;
  u32 n0 = rb * 128, m0 = cb * 128;

  // Stage B tile: pre-swizzled GLOBAL source, linear LDS dest.
  const char* Bg = (const char*)(Sb + (size_t)m0 * DIM);
#pragma unroll
  for (int i = 0; i < 8; i++) {
    u32 lb = (u32)(i * 4 + wv) * 1024u;
    u32 go = swz(lb + (u32)ln * 16u);
    __builtin_amdgcn_global_load_lds((const __attribute__((address_space(1))) void*)(Bg + go),
                                     (__attribute__((address_space(3))) void*)((char*)Bt + lb),
                                     16, 0, 0);
  }

  int wr = wv >> 1, wc = wv & 1;
  int rbw = wr * 64, cbw = wc * 64;
  int lr = ln & 15, lg = ln >> 4;

  // A fragments direct to registers (L2/L3-resident bf16 X).
  bf16x8 af[4][4];
  const u16* Abase = Xb + (size_t)(n0 + rbw) * DIM;
#pragma unroll
  for (int i = 0; i < 4; i++)
#pragma unroll
    for (int kk = 0; kk < 4; kk++)
      af[i][kk] = *(const bf16x8*)(Abase + (i * 16 + lr) * DIM + kk * 32 + lg * 8);

  if (t < 128) {
    lx2[t] = x2[n0 + t];
    ls2[t] = s2[m0 + t];
    if (WRITE) lscale[t] = invs[m0 + t];
  }
  __syncthreads();

  f32x4 acc[4][4];
#pragma unroll
  for (int i = 0; i < 4; i++)
#pragma unroll
    for (int j = 0; j < 4; j++) acc[i][j] = (f32x4){0.f, 0.f, 0.f, 0.f};

#pragma unroll
  for (int kk = 0; kk < 4; kk++) {
    bf16x8 bfr[4];
#pragma unroll
    for (int j = 0; j < 4; j++)
      bfr[j] = *(const bf16x8*)((const char*)Bt +
               swz((u32)((cbw + j * 16 + lr) * 256 + kk * 64 + lg * 16)));
#pragma unroll
    for (int i = 0; i < 4; i++)
#pragma unroll
      for (int j = 0; j < 4; j++) {
        if (WRITE)
          acc[i][j] = __builtin_amdgcn_mfma_f32_16x16x32_bf16(bfr[j], af[i][kk], acc[i][j], 0, 0, 0);
        else
          acc[i][j] = __builtin_amdgcn_mfma_f32_16x16x32_bf16(af[i][kk], bfr[j], acc[i][j], 0, 0, 0);
      }
  }

  if (WRITE) {
    // D layout (swapped): row=(lane>>4)*4+reg -> m, col=lane&15 -> n.
#pragma unroll
    for (int i = 0; i < 4; i++) {
      int n = rbw + i * 16 + lr;
      float xx = lx2[n];
      float* orow = outp + (size_t)(n0 + n) * MCB + m0;
#pragma unroll
      for (int j = 0; j < 4; j++) {
        int mb = cbw + j * 16 + lg * 4;
        f32x4 v;
#pragma unroll
        for (int r = 0; r < 4; r++) {
          float d2 = xx + ls2[mb + r] - 2.f * acc[i][j][r];
          d2 = fmaxf(d2, 0.f);
          float e = __expf(-__fsqrt_rn(d2));
          v[r] = e * lscale[mb + r];
        }
        __builtin_nontemporal_store(v, (f32x4*)(orow + mb));
      }
    }
  } else {
    // D layout (normal): row -> n (in-lane over r), col=lane&15 -> m.
    float csum[4] = {0.f, 0.f, 0.f, 0.f};
#pragma unroll
    for (int i = 0; i < 4; i++) {
#pragma unroll
      for (int j = 0; j < 4; j++) {
        int m = cbw + j * 16 + lr;
        float ss = ls2[m];
#pragma unroll
        for (int r = 0; r < 4; r++) {
          int n = rbw + i * 16 + lg * 4 + r;
          float d2 = lx2[n] + ss - 2.f * acc[i][j][r];
          d2 = fmaxf(d2, 0.f);
          csum[j] += __expf(-__fsqrt_rn(d2));
        }
      }
    }
    // Reduce across the 4 lane-groups (bits 4,5); lanes 0..15 hold col sums.
#pragma unroll
    for (int j = 0; j < 4; j++) {
      float v = csum[j];
      v += __shfl_xor(v, 16);
      v += __shfl_xor(v, 32);
      if (ln < 16) colsum2[wv][j * 16 + ln] = v;
    }
    __syncthreads();
    if (t < 128) {
      int wcf = t >> 6, lc = t & 63;
      outp[(size_t)rb * MCB + m0 + t] = colsum2[wcf][lc] + colsum2[wcf + 2][lc];
    }
  }
}

// Sum the 1024 per-row-block partials per column, emit 1/sum. Deterministic.
__global__ __launch_bounds__(256) void reduce_cols(const float* __restrict__ partial,
                                                   float* __restrict__ invs) {
  int m = blockIdx.x, t = threadIdx.x;
  float s = 0.f;
  for (int k = t; k < NRB; k += 256) s += partial[(size_t)k * MCB + m];
  s += __shfl_xor(s, 1);  s += __shfl_xor(s, 2);  s += __shfl_xor(s, 4);
  s += __shfl_xor(s, 8);  s += __shfl_xor(s, 16); s += __shfl_xor(s, 32);
  __shared__ float w4[4];
  if ((t & 63) == 0) w4[t >> 6] = s;
  __syncthreads();
  if (t == 0) invs[m] = 1.0f / (w4[0] + w4[1] + w4[2] + w4[3]);
}

extern "C" void kernel_launch(void* const* d_in, const int* in_sizes, int n_in,
                              void* d_out, int out_size, void* d_ws, size_t ws_size,
                              hipStream_t stream) {
  const float* X = (const float*)d_in[0];
  const float* S = (const float*)d_in[1];
  float* out = (float*)d_out;
  char* ws = (char*)d_ws;

  // ws layout (256B-aligned), total ~36.3 MB:
  u16*   Xb      = (u16*)ws;                      // 131072*128*2 = 33554432
  u16*   Sb      = (u16*)(ws + 33554432);         // 512*128*2    = 131072
  float* x2      = (float*)(ws + 33685504);       // 131072*4     = 524288
  float* s2      = (float*)(ws + 34209792);       // 512*4        = 2048
  float* invs    = (float*)(ws + 34211840);       // 512*4        = 2048
  float* partial = (float*)(ws + 34213888);       // 1024*512*4   = 2097152

  convert_rows<<<2048, 256, 0, stream>>>(X, Xb, x2, NPTS);
  convert_rows<<<64, 256, 0, stream>>>(S, Sb, s2, MCB);
  gemm_pass<0><<<NBLK, 256, 0, stream>>>(Xb, Sb, x2, s2, invs, partial);
  reduce_cols<<<MCB, 256, 0, stream>>>(partial, invs);
  gemm_pass<1><<<NBLK, 256, 0, stream>>>(Xb, Sb, x2, s2, invs, out);
}